// Round 14
// baseline (197.449 us; speedup 1.0000x reference)
//
#include <hip/hip_runtime.h>
#include <cstdint>
#include <cstddef>

#define NN 8192
#define NE 131072
#define EMB 256

typedef float f32x4 __attribute__((ext_vector_type(4)));
typedef __bf16 bf16x8 __attribute__((ext_vector_type(8)));

__device__ __forceinline__ unsigned short f2bf(float f) {
  unsigned u = __float_as_uint(f);
  u += 0x7fffu + ((u >> 16) & 1u);   // round-to-nearest-even
  return (unsigned short)(u >> 16);
}

__device__ __forceinline__ void gload_lds16(const void* g, void* l) {
  __builtin_amdgcn_global_load_lds(
      (const __attribute__((address_space(1))) unsigned int*)g,
      (__attribute__((address_space(3))) unsigned int*)l, 16, 0, 0);
}

// ---------- node head + bf16 convert + sq norms (must precede adj) ----------
__global__ __launch_bounds__(256) void node_prep_kernel(const float* __restrict__ X,
                                                        const float* __restrict__ w,
                                                        const float* __restrict__ bias,
                                                        float* __restrict__ out,
                                                        unsigned short* __restrict__ Xb,
                                                        float* __restrict__ sq) {
  __shared__ float xs[16 * 260];
  int tid = threadIdx.x;
  int n0  = blockIdx.x * 16;
  int r   = tid >> 4, g = tid & 15;

  float s = 0.f;
  #pragma unroll
  for (int kc = 0; kc < 4; ++kc) {
    float4 v = *(const float4*)(X + (size_t)(n0 + r) * EMB + kc * 64 + g * 4);
    *(float4*)(&xs[r * 260 + kc * 64 + g * 4]) = v;
    s += v.x * v.x + v.y * v.y + v.z * v.z + v.w * v.w;
    ushort4 b;
    b.x = f2bf(v.x); b.y = f2bf(v.y); b.z = f2bf(v.z); b.w = f2bf(v.w);
    *(ushort4*)(Xb + (size_t)(n0 + r) * EMB + kc * 64 + g * 4) = b;
  }
  s += __shfl_xor(s, 1); s += __shfl_xor(s, 2);
  s += __shfl_xor(s, 4); s += __shfl_xor(s, 8);
  if (g == 0) sq[n0 + r] = s;
  __syncthreads();

  int o0 = g * 4;
  float acc[4] = {0.f, 0.f, 0.f, 0.f};
  #pragma unroll 4
  for (int k = 0; k < 256; k += 4) {
    float4 x = *(const float4*)(&xs[r * 260 + k]);
    #pragma unroll
    for (int oo = 0; oo < 4; ++oo) {
      float4 wv = *(const float4*)(w + (size_t)(o0 + oo) * EMB + k);
      acc[oo] = fmaf(x.x, wv.x, fmaf(x.y, wv.y, fmaf(x.z, wv.z, fmaf(x.w, wv.w, acc[oo]))));
    }
  }
  float4 o;
  o.x = acc[0] + bias[o0 + 0];
  o.y = acc[1] + bias[o0 + 1];
  o.z = acc[2] + bias[o0 + 2];
  o.w = acc[3] + bias[o0 + 3];
  *(float4*)(out + (size_t)(n0 + r) * 64 + o0) = o;
}

// ---------- mega: adj + edge, EXACT per-XCD bookkeeping, tj-major write map ----------
// b&7 = XCD x (blocks round-robin XCDs); s = b>>3 = per-XCD slot 0..575.
// Slot s%9==8 -> edge block (64 per XCD). Else adj: a = s - s/9 in 0..511,
//   ti = a&63 (sweeps fast), tj = x*8 + (a>>6) (8 fixed row-bands per XCD).
// => temporally-adjacent blocks on an XCD write ADJACENT 512B column segments of
// the SAME 128 output rows: page-sequential HBM write stream; B-panel L2-resident.
__global__ __launch_bounds__(256) void mega_kernel(const unsigned short* __restrict__ Xb,
                                                   const float* __restrict__ sq,
                                                   const float* __restrict__ Wp,
                                                   const float* __restrict__ bp,
                                                   float* __restrict__ adj_out,
                                                   const float* __restrict__ Xe,
                                                   const float* __restrict__ ew,
                                                   const float* __restrict__ eb,
                                                   float* __restrict__ edge_out) {
  __shared__ __align__(16) char smem[32768];
  int tid = threadIdx.x;
  int b   = blockIdx.x;           // 0..4607
  int x   = b & 7;                // XCD (exact)
  int s   = b >> 3;               // per-XCD slot 0..575

  if (s % 9 == 8) {
    // ===== edge head: 256 edges/block =====
    float* lds = (float*)smem;    // 17.4 KB
    int e0 = (x * 64 + s / 9) * 256;
    int lr = tid >> 2, lc = (tid & 3) * 4;

    float4 v[4];
    #pragma unroll
    for (int q = 0; q < 4; ++q)
      v[q] = *(const float4*)(Xe + (size_t)(e0 + lr + q * 64) * EMB + lc);

    float acc[16];
    #pragma unroll
    for (int o = 0; o < 16; ++o) acc[o] = 0.f;

    for (int kc = 0; kc < 16; ++kc) {
      __syncthreads();
      #pragma unroll
      for (int q = 0; q < 4; ++q) {
        float* d = &lds[(lr + q * 64) * 17 + lc];
        d[0] = v[q].x; d[1] = v[q].y; d[2] = v[q].z; d[3] = v[q].w;
      }
      __syncthreads();
      if (kc < 15) {
        #pragma unroll
        for (int q = 0; q < 4; ++q)
          v[q] = *(const float4*)(Xe + (size_t)(e0 + lr + q * 64) * EMB + (kc + 1) * 16 + lc);
      }
      const float* wk0 = ew + kc * 16;   // uniform -> s_load
      #pragma unroll
      for (int k = 0; k < 16; ++k) {
        float xv = lds[tid * 17 + k];
        #pragma unroll
        for (int o = 0; o < 16; ++o)
          acc[o] = fmaf(xv, wk0[(size_t)o * EMB + k], acc[o]);
      }
    }
    #pragma unroll
    for (int o = 0; o < 16; ++o) acc[o] += eb[o];
    float4* dst = (float4*)(edge_out + (size_t)(e0 + tid) * 16);
    dst[0] = make_float4(acc[0], acc[1], acc[2], acc[3]);
    dst[1] = make_float4(acc[4], acc[5], acc[6], acc[7]);
    dst[2] = make_float4(acc[8], acc[9], acc[10], acc[11]);
    dst[3] = make_float4(acc[12], acc[13], acc[14], acc[15]);
    return;
  }

  // ===== adj 128x128 tile, BK=32, dbuf, counted vmcnt(4) (R9 staging) =====
  int a  = s - s / 9;                  // 0..511
  int ti = a & 63;                     // column panel: sweeps consecutively
  int tj = x * 8 + (a >> 6);           // row band: fixed per XCD for 64 blocks

  int wave = tid >> 6, lane = tid & 63;
  int wr = (wave >> 1) * 64;
  int wc = (wave & 1) * 64;
  int l15 = lane & 15, lg = lane >> 4;

  f32x4 acc[4][4] = {};

  int srow0 = wave * 32 + (lane >> 2);
  int sp    = lane & 3;

  const size_t rowA = (size_t)(ti * 128) * EMB;
  const size_t rowB = (size_t)(tj * 128) * EMB;

#define STAGE(BUF, KT)                                                          \
  {                                                                             \
    char* base = smem + (BUF) * 16384;                                          \
    int r0 = srow0, r1 = srow0 + 16;                                            \
    int c0 = (KT) * 32 + ((sp ^ ((r0 >> 1) & 3)) << 3);                         \
    int c1 = (KT) * 32 + ((sp ^ ((r1 >> 1) & 3)) << 3);                         \
    gload_lds16(Xb + rowA + (size_t)r0 * EMB + c0, base + wave * 2048);         \
    gload_lds16(Xb + rowA + (size_t)r1 * EMB + c1, base + wave * 2048 + 1024);  \
    gload_lds16(Xb + rowB + (size_t)r0 * EMB + c0, base + 8192 + wave * 2048);  \
    gload_lds16(Xb + rowB + (size_t)r1 * EMB + c1, base + 8192 + wave * 2048 + 1024); \
  }

  STAGE(0, 0)

  #pragma unroll
  for (int kt = 0; kt < 8; ++kt) {
    if (kt < 7) {
      STAGE((kt + 1) & 1, kt + 1)
      asm volatile("s_waitcnt vmcnt(4)" ::: "memory");
    } else {
      asm volatile("s_waitcnt vmcnt(0)" ::: "memory");
    }
    __builtin_amdgcn_sched_barrier(0);
    __builtin_amdgcn_s_barrier();
    __builtin_amdgcn_sched_barrier(0);

    const char* Ab = smem + (kt & 1) * 16384;
    const char* Bb = Ab + 8192;
    bf16x8 af[4], bfr[4];
    #pragma unroll
    for (int m = 0; m < 4; ++m) {
      int rr = wr + m * 16 + l15;
      af[m] = *(const bf16x8*)(Ab + rr * 64 + ((lg ^ ((rr >> 1) & 3)) << 4));
    }
    #pragma unroll
    for (int n = 0; n < 4; ++n) {
      int rr = wc + n * 16 + l15;
      bfr[n] = *(const bf16x8*)(Bb + rr * 64 + ((lg ^ ((rr >> 1) & 3)) << 4));
    }
    #pragma unroll
    for (int m = 0; m < 4; ++m)
      #pragma unroll
      for (int n = 0; n < 4; ++n)
        acc[m][n] = __builtin_amdgcn_mfma_f32_16x16x32_bf16(af[m], bfr[n], acc[m][n], 0, 0, 0);

    __builtin_amdgcn_sched_barrier(0);
    __builtin_amdgcn_s_barrier();
    __builtin_amdgcn_sched_barrier(0);
  }
#undef STAGE

  // ---- sigmoid + diag mask, in registers ----
  float W0 = Wp[0], b0 = bp[0];
  float w2 = -2.0f * W0;
  int col0 = tj * 128 + wc + l15;
  int row0 = ti * 128 + wr + (lg << 2);
  bool diag = (ti == tj);

  float aiW[16];
  #pragma unroll
  for (int m = 0; m < 4; ++m)
    #pragma unroll
    for (int rg = 0; rg < 4; ++rg)
      aiW[m * 4 + rg] = W0 * sq[row0 + m * 16 + rg];

  #pragma unroll
  for (int n = 0; n < 4; ++n) {
    int j = col0 + n * 16;
    float sjW = fmaf(W0, sq[j], b0);
    #pragma unroll
    for (int m = 0; m < 4; ++m) {
      #pragma unroll
      for (int rg = 0; rg < 4; ++rg) {
        float t = fmaf(w2, acc[m][n][rg], aiW[m * 4 + rg] + sjW);
        acc[m][n][rg] = __builtin_amdgcn_rcpf(1.0f + __expf(-t));
      }
      if (diag) {
        #pragma unroll
        for (int rg = 0; rg < 4; ++rg)
          if (row0 + m * 16 + rg == j) acc[m][n][rg] = 0.0f;
      }
    }
  }

  // ---- LDS acc transpose (R11): 2x512B contiguous runs per store instr ----
  float* T = (float*)smem;   // 16.9 KB
  int wcbit = wc >> 6;
  #pragma unroll
  for (int p = 0; p < 4; ++p) {
    asm volatile("s_waitcnt lgkmcnt(0)" ::: "memory");
    __builtin_amdgcn_sched_barrier(0);
    __builtin_amdgcn_s_barrier();
    __builtin_amdgcn_sched_barrier(0);

    if (wcbit == (p >> 1)) {
      #pragma unroll
      for (int nn = 0; nn < 2; ++nn) {
        int n  = 2 * (p & 1) + nn;
        int jl = nn * 16 + l15;
        #pragma unroll
        for (int m = 0; m < 4; ++m)
          *(f32x4*)(&T[132 * jl + wr + m * 16 + (lg << 2)]) = acc[m][n];
      }
    }
    asm volatile("s_waitcnt lgkmcnt(0)" ::: "memory");
    __builtin_amdgcn_sched_barrier(0);
    __builtin_amdgcn_s_barrier();
    __builtin_amdgcn_sched_barrier(0);

    int ic = (lane & 31) << 2;
    #pragma unroll
    for (int qq = 0; qq < 4; ++qq) {
      int jl = wave * 8 + qq * 2 + (lane >> 5);
      f32x4 v = *(const f32x4*)(&T[132 * jl + ic]);
      int jg = tj * 128 + p * 32 + jl;
      __builtin_nontemporal_store(v,
          (f32x4*)(&adj_out[(size_t)jg * NN + ti * 128 + ic]));
    }
  }
}

extern "C" void kernel_launch(void* const* d_in, const int* in_sizes, int n_in,
                              void* d_out, int out_size, void* d_ws, size_t ws_size,
                              hipStream_t stream) {
  const float* node_emb = (const float*)d_in[0];
  const float* edge_emb = (const float*)d_in[1];
  const float* node_w   = (const float*)d_in[2];
  const float* node_b   = (const float*)d_in[3];
  const float* edge_w   = (const float*)d_in[4];
  const float* edge_b   = (const float*)d_in[5];
  const float* Wp       = (const float*)d_in[6];
  const float* bp       = (const float*)d_in[7];

  float* out      = (float*)d_out;
  float* node_out = out;                        // [8192 x 64]
  float* edge_out = out + (size_t)NN * 64;      // [131072 x 16]
  float* adj_out  = out + (size_t)NN * 64 + (size_t)NE * 16;  // [8192 x 8192]

  unsigned short* Xb = (unsigned short*)d_ws;                       // 4 MiB
  float* sq = (float*)((char*)d_ws + (size_t)NN * EMB * 2);         // 32 KiB

  node_prep_kernel<<<dim3(512), dim3(256), 0, stream>>>(node_emb, node_w, node_b,
                                                        node_out, Xb, sq);
  mega_kernel<<<dim3(4608), dim3(256), 0, stream>>>(Xb, sq, Wp, bp, adj_out,
                                                    edge_emb, edge_w, edge_b, edge_out);
}

// Round 15
// 179.028 us; speedup vs baseline: 1.1029x; 1.1029x over previous
//
#include <hip/hip_runtime.h>
#include <cstdint>
#include <cstddef>

#define NN 8192
#define NE 131072
#define EMB 256

typedef float f32x4 __attribute__((ext_vector_type(4)));
typedef __bf16 bf16x8 __attribute__((ext_vector_type(8)));

__device__ __forceinline__ unsigned short f2bf(float f) {
  unsigned u = __float_as_uint(f);
  u += 0x7fffu + ((u >> 16) & 1u);   // round-to-nearest-even
  return (unsigned short)(u >> 16);
}

__device__ __forceinline__ void gload_lds16(const void* g, void* l) {
  __builtin_amdgcn_global_load_lds(
      (const __attribute__((address_space(1))) unsigned int*)g,
      (__attribute__((address_space(3))) unsigned int*)l, 16, 0, 0);
}

// ---------- node head + bf16 convert + sq norms (must precede adj) ----------
__global__ __launch_bounds__(256) void node_prep_kernel(const float* __restrict__ X,
                                                        const float* __restrict__ w,
                                                        const float* __restrict__ bias,
                                                        float* __restrict__ out,
                                                        unsigned short* __restrict__ Xb,
                                                        float* __restrict__ sq) {
  __shared__ float xs[16 * 260];
  int tid = threadIdx.x;
  int n0  = blockIdx.x * 16;
  int r   = tid >> 4, g = tid & 15;

  float s = 0.f;
  #pragma unroll
  for (int kc = 0; kc < 4; ++kc) {
    float4 v = *(const float4*)(X + (size_t)(n0 + r) * EMB + kc * 64 + g * 4);
    *(float4*)(&xs[r * 260 + kc * 64 + g * 4]) = v;
    s += v.x * v.x + v.y * v.y + v.z * v.z + v.w * v.w;
    ushort4 b;
    b.x = f2bf(v.x); b.y = f2bf(v.y); b.z = f2bf(v.z); b.w = f2bf(v.w);
    *(ushort4*)(Xb + (size_t)(n0 + r) * EMB + kc * 64 + g * 4) = b;
  }
  s += __shfl_xor(s, 1); s += __shfl_xor(s, 2);
  s += __shfl_xor(s, 4); s += __shfl_xor(s, 8);
  if (g == 0) sq[n0 + r] = s;
  __syncthreads();

  int o0 = g * 4;
  float acc[4] = {0.f, 0.f, 0.f, 0.f};
  #pragma unroll 4
  for (int k = 0; k < 256; k += 4) {
    float4 x = *(const float4*)(&xs[r * 260 + k]);
    #pragma unroll
    for (int oo = 0; oo < 4; ++oo) {
      float4 wv = *(const float4*)(w + (size_t)(o0 + oo) * EMB + k);
      acc[oo] = fmaf(x.x, wv.x, fmaf(x.y, wv.y, fmaf(x.z, wv.z, fmaf(x.w, wv.w, acc[oo]))));
    }
  }
  float4 o;
  o.x = acc[0] + bias[o0 + 0];
  o.y = acc[1] + bias[o0 + 1];
  o.z = acc[2] + bias[o0 + 2];
  o.w = acc[3] + bias[o0 + 3];
  *(float4*)(out + (size_t)(n0 + r) * 64 + o0) = o;
}

// ---------- mega: adj 128x128 tiles (4096) + edge head (512), 1:8 interleave ----------
// R15 = R9 (best known: 168.2) with three zero-VGPR trims:
//  (1) edge blocks FIRST (rem==0): their pure-read burst overlaps adj's read-heavy
//      ramp; adj's store-heavy tail runs uncontended.
//  (2) final end-of-K-loop barrier pair removed (epilogue touches no LDS) — waves
//      desync into the store phase earlier, widening the store-issue window.
//  (3) W/b loaded before the K-loop.
__global__ __launch_bounds__(256) void mega_kernel(const unsigned short* __restrict__ Xb,
                                                   const float* __restrict__ sq,
                                                   const float* __restrict__ Wp,
                                                   const float* __restrict__ bp,
                                                   float* __restrict__ adj_out,
                                                   const float* __restrict__ Xe,
                                                   const float* __restrict__ ew,
                                                   const float* __restrict__ eb,
                                                   float* __restrict__ edge_out) {
  __shared__ __align__(16) char smem[32768];
  int tid = threadIdx.x;
  int b   = blockIdx.x;           // 0..4607
  int g   = b / 9, rem = b - g * 9;

  if (rem == 0) {
    // ===== edge head: 256 edges/block =====
    float* lds = (float*)smem;    // 17.4 KB
    int e0 = g * 256;
    int lr = tid >> 2, lc = (tid & 3) * 4;

    float4 v[4];
    #pragma unroll
    for (int q = 0; q < 4; ++q)
      v[q] = *(const float4*)(Xe + (size_t)(e0 + lr + q * 64) * EMB + lc);

    float acc[16];
    #pragma unroll
    for (int o = 0; o < 16; ++o) acc[o] = 0.f;

    for (int kc = 0; kc < 16; ++kc) {
      __syncthreads();
      #pragma unroll
      for (int q = 0; q < 4; ++q) {
        float* d = &lds[(lr + q * 64) * 17 + lc];
        d[0] = v[q].x; d[1] = v[q].y; d[2] = v[q].z; d[3] = v[q].w;
      }
      __syncthreads();
      if (kc < 15) {
        #pragma unroll
        for (int q = 0; q < 4; ++q)
          v[q] = *(const float4*)(Xe + (size_t)(e0 + lr + q * 64) * EMB + (kc + 1) * 16 + lc);
      }
      const float* wk0 = ew + kc * 16;   // uniform -> s_load
      #pragma unroll
      for (int k = 0; k < 16; ++k) {
        float x = lds[tid * 17 + k];
        #pragma unroll
        for (int o = 0; o < 16; ++o)
          acc[o] = fmaf(x, wk0[(size_t)o * EMB + k], acc[o]);
      }
    }
    #pragma unroll
    for (int o = 0; o < 16; ++o) acc[o] += eb[o];
    float4* dst = (float4*)(edge_out + (size_t)(e0 + tid) * 16);
    dst[0] = make_float4(acc[0], acc[1], acc[2], acc[3]);
    dst[1] = make_float4(acc[4], acc[5], acc[6], acc[7]);
    dst[2] = make_float4(acc[8], acc[9], acc[10], acc[11]);
    dst[3] = make_float4(acc[12], acc[13], acc[14], acc[15]);
    return;
  }

  // ===== adj 128x128 tile, BK=32, dbuf, counted vmcnt(4) (R9 staging) =====
  int adjid = g * 8 + (rem - 1);
  int low3  = adjid & 7, q = adjid >> 3;
  int ti = low3 * 8 + (q & 7);                     // 8 slowly-rotating A-panels
  int tj = ((q >> 6) & 7) * 8 + ((q >> 3) & 7);    // B-panel advances slowly

  int wave = tid >> 6, lane = tid & 63;
  int wr = (wave >> 1) * 64;
  int wc = (wave & 1) * 64;
  int l15 = lane & 15, lg = lane >> 4;

  float W0 = Wp[0], b0 = bp[0];   // uniform s_loads, hoisted before the K-loop

  f32x4 acc[4][4] = {};

  int srow0 = wave * 32 + (lane >> 2);
  int sp    = lane & 3;

  const size_t rowA = (size_t)(ti * 128) * EMB;
  const size_t rowB = (size_t)(tj * 128) * EMB;

#define STAGE(BUF, KT)                                                          \
  {                                                                             \
    char* base = smem + (BUF) * 16384;                                          \
    int r0 = srow0, r1 = srow0 + 16;                                            \
    int c0 = (KT) * 32 + ((sp ^ ((r0 >> 1) & 3)) << 3);                         \
    int c1 = (KT) * 32 + ((sp ^ ((r1 >> 1) & 3)) << 3);                         \
    gload_lds16(Xb + rowA + (size_t)r0 * EMB + c0, base + wave * 2048);         \
    gload_lds16(Xb + rowA + (size_t)r1 * EMB + c1, base + wave * 2048 + 1024);  \
    gload_lds16(Xb + rowB + (size_t)r0 * EMB + c0, base + 8192 + wave * 2048);  \
    gload_lds16(Xb + rowB + (size_t)r1 * EMB + c1, base + 8192 + wave * 2048 + 1024); \
  }

  STAGE(0, 0)

  #pragma unroll
  for (int kt = 0; kt < 8; ++kt) {
    if (kt < 7) {
      STAGE((kt + 1) & 1, kt + 1)
      asm volatile("s_waitcnt vmcnt(4)" ::: "memory");
    } else {
      asm volatile("s_waitcnt vmcnt(0)" ::: "memory");
    }
    __builtin_amdgcn_sched_barrier(0);
    __builtin_amdgcn_s_barrier();
    __builtin_amdgcn_sched_barrier(0);

    const char* Ab = smem + (kt & 1) * 16384;
    const char* Bb = Ab + 8192;
    bf16x8 af[4], bfr[4];
    #pragma unroll
    for (int m = 0; m < 4; ++m) {
      int rr = wr + m * 16 + l15;
      af[m] = *(const bf16x8*)(Ab + rr * 64 + ((lg ^ ((rr >> 1) & 3)) << 4));
    }
    #pragma unroll
    for (int n = 0; n < 4; ++n) {
      int rr = wc + n * 16 + l15;
      bfr[n] = *(const bf16x8*)(Bb + rr * 64 + ((lg ^ ((rr >> 1) & 3)) << 4));
    }
    #pragma unroll
    for (int m = 0; m < 4; ++m)
      #pragma unroll
      for (int n = 0; n < 4; ++n)
        acc[m][n] = __builtin_amdgcn_mfma_f32_16x16x32_bf16(af[m], bfr[n], acc[m][n], 0, 0, 0);

    if (kt < 7) {   // final barrier pair removed: epilogue touches no LDS
      __builtin_amdgcn_sched_barrier(0);
      __builtin_amdgcn_s_barrier();
      __builtin_amdgcn_sched_barrier(0);
    }
  }
#undef STAGE

  // ---- sigmoid + diag mask + transposed-square NT store (R9 epilogue) ----
  float w2 = -2.0f * W0;
  int col0 = tj * 128 + wc + l15;
  int row0 = ti * 128 + wr + (lg << 2);
  bool diag = (ti == tj);

  float aiW[16];
  #pragma unroll
  for (int m = 0; m < 4; ++m)
    #pragma unroll
    for (int rg = 0; rg < 4; ++rg)
      aiW[m * 4 + rg] = W0 * sq[row0 + m * 16 + rg];

  #pragma unroll
  for (int n = 0; n < 4; ++n) {
    int j = col0 + n * 16;
    float sjW = fmaf(W0, sq[j], b0);
    #pragma unroll
    for (int m = 0; m < 4; ++m) {
      #pragma unroll
      for (int rg = 0; rg < 4; ++rg) {
        float t = fmaf(w2, acc[m][n][rg], aiW[m * 4 + rg] + sjW);
        acc[m][n][rg] = __builtin_amdgcn_rcpf(1.0f + __expf(-t));
      }
      if (diag) {
        #pragma unroll
        for (int rg = 0; rg < 4; ++rg)
          if (row0 + m * 16 + rg == j) acc[m][n][rg] = 0.0f;
      }
      __builtin_nontemporal_store(acc[m][n],
          (f32x4*)(&adj_out[(size_t)j * NN + row0 + m * 16]));
    }
  }
}

extern "C" void kernel_launch(void* const* d_in, const int* in_sizes, int n_in,
                              void* d_out, int out_size, void* d_ws, size_t ws_size,
                              hipStream_t stream) {
  const float* node_emb = (const float*)d_in[0];
  const float* edge_emb = (const float*)d_in[1];
  const float* node_w   = (const float*)d_in[2];
  const float* node_b   = (const float*)d_in[3];
  const float* edge_w   = (const float*)d_in[4];
  const float* edge_b   = (const float*)d_in[5];
  const float* Wp       = (const float*)d_in[6];
  const float* bp       = (const float*)d_in[7];

  float* out      = (float*)d_out;
  float* node_out = out;                        // [8192 x 64]
  float* edge_out = out + (size_t)NN * 64;      // [131072 x 16]
  float* adj_out  = out + (size_t)NN * 64 + (size_t)NE * 16;  // [8192 x 8192]

  unsigned short* Xb = (unsigned short*)d_ws;                       // 4 MiB
  float* sq = (float*)((char*)d_ws + (size_t)NN * EMB * 2);         // 32 KiB

  node_prep_kernel<<<dim3(512), dim3(256), 0, stream>>>(node_emb, node_w, node_b,
                                                        node_out, Xb, sq);
  mega_kernel<<<dim3(4608), dim3(256), 0, stream>>>(Xb, sq, Wp, bp, adj_out,
                                                    edge_emb, edge_w, edge_b, edge_out);
}

// Round 16
// 167.894 us; speedup vs baseline: 1.1760x; 1.0663x over previous
//
#include <hip/hip_runtime.h>
#include <cstdint>
#include <cstddef>

#define NN 8192
#define NE 131072
#define EMB 256

typedef float f32x4 __attribute__((ext_vector_type(4)));
typedef __bf16 bf16x8 __attribute__((ext_vector_type(8)));

__device__ __forceinline__ unsigned short f2bf(float f) {
  unsigned u = __float_as_uint(f);
  u += 0x7fffu + ((u >> 16) & 1u);   // round-to-nearest-even
  return (unsigned short)(u >> 16);
}

__device__ __forceinline__ void gload_lds16(const void* g, void* l) {
  __builtin_amdgcn_global_load_lds(
      (const __attribute__((address_space(1))) unsigned int*)g,
      (__attribute__((address_space(3))) unsigned int*)l, 16, 0, 0);
}

// ---------- node head + bf16 convert + sq norms (must precede adj) ----------
__global__ __launch_bounds__(256) void node_prep_kernel(const float* __restrict__ X,
                                                        const float* __restrict__ w,
                                                        const float* __restrict__ bias,
                                                        float* __restrict__ out,
                                                        unsigned short* __restrict__ Xb,
                                                        float* __restrict__ sq) {
  __shared__ float xs[16 * 260];
  int tid = threadIdx.x;
  int n0  = blockIdx.x * 16;
  int r   = tid >> 4, g = tid & 15;

  float s = 0.f;
  #pragma unroll
  for (int kc = 0; kc < 4; ++kc) {
    float4 v = *(const float4*)(X + (size_t)(n0 + r) * EMB + kc * 64 + g * 4);
    *(float4*)(&xs[r * 260 + kc * 64 + g * 4]) = v;
    s += v.x * v.x + v.y * v.y + v.z * v.z + v.w * v.w;
    ushort4 b;
    b.x = f2bf(v.x); b.y = f2bf(v.y); b.z = f2bf(v.z); b.w = f2bf(v.w);
    *(ushort4*)(Xb + (size_t)(n0 + r) * EMB + kc * 64 + g * 4) = b;
  }
  s += __shfl_xor(s, 1); s += __shfl_xor(s, 2);
  s += __shfl_xor(s, 4); s += __shfl_xor(s, 8);
  if (g == 0) sq[n0 + r] = s;
  __syncthreads();

  int o0 = g * 4;
  float acc[4] = {0.f, 0.f, 0.f, 0.f};
  #pragma unroll 4
  for (int k = 0; k < 256; k += 4) {
    float4 x = *(const float4*)(&xs[r * 260 + k]);
    #pragma unroll
    for (int oo = 0; oo < 4; ++oo) {
      float4 wv = *(const float4*)(w + (size_t)(o0 + oo) * EMB + k);
      acc[oo] = fmaf(x.x, wv.x, fmaf(x.y, wv.y, fmaf(x.z, wv.z, fmaf(x.w, wv.w, acc[oo]))));
    }
  }
  float4 o;
  o.x = acc[0] + bias[o0 + 0];
  o.y = acc[1] + bias[o0 + 1];
  o.z = acc[2] + bias[o0 + 2];
  o.w = acc[3] + bias[o0 + 3];
  *(float4*)(out + (size_t)(n0 + r) * 64 + o0) = o;
}

// ---------- mega: adj 128x128 tiles (4096) + edge head (512), 8:1 interleave ----------
// R16 == R9 exactly (best measured: 168.2 µs total). LDS swizzle slot = sp^((r>>1)&3)
// (2-way-free on ds_read_b128); T4 counted vmcnt(4) keeps next tile's prefetch in
// flight across the barrier; dbuf BK=32; transposed-square NT store epilogue.
__global__ __launch_bounds__(256) void mega_kernel(const unsigned short* __restrict__ Xb,
                                                   const float* __restrict__ sq,
                                                   const float* __restrict__ Wp,
                                                   const float* __restrict__ bp,
                                                   float* __restrict__ adj_out,
                                                   const float* __restrict__ Xe,
                                                   const float* __restrict__ ew,
                                                   const float* __restrict__ eb,
                                                   float* __restrict__ edge_out) {
  __shared__ __align__(16) char smem[32768];
  int tid = threadIdx.x;
  int b   = blockIdx.x;           // 0..4607
  int g   = b / 9, rem = b - g * 9;

  if (rem == 8) {
    // ===== edge head: 256 edges/block =====
    float* lds = (float*)smem;    // 256*17 floats = 17.4 KB
    int e0 = g * 256;
    int lr = tid >> 2, lc = (tid & 3) * 4;

    float4 v[4];
    #pragma unroll
    for (int q = 0; q < 4; ++q)
      v[q] = *(const float4*)(Xe + (size_t)(e0 + lr + q * 64) * EMB + lc);

    float acc[16];
    #pragma unroll
    for (int o = 0; o < 16; ++o) acc[o] = 0.f;

    for (int kc = 0; kc < 16; ++kc) {
      __syncthreads();
      #pragma unroll
      for (int q = 0; q < 4; ++q) {
        float* d = &lds[(lr + q * 64) * 17 + lc];
        d[0] = v[q].x; d[1] = v[q].y; d[2] = v[q].z; d[3] = v[q].w;
      }
      __syncthreads();
      if (kc < 15) {
        #pragma unroll
        for (int q = 0; q < 4; ++q)
          v[q] = *(const float4*)(Xe + (size_t)(e0 + lr + q * 64) * EMB + (kc + 1) * 16 + lc);
      }
      const float* wk0 = ew + kc * 16;   // uniform -> s_load
      #pragma unroll
      for (int k = 0; k < 16; ++k) {
        float x = lds[tid * 17 + k];
        #pragma unroll
        for (int o = 0; o < 16; ++o)
          acc[o] = fmaf(x, wk0[(size_t)o * EMB + k], acc[o]);
      }
    }
    #pragma unroll
    for (int o = 0; o < 16; ++o) acc[o] += eb[o];
    float4* dst = (float4*)(edge_out + (size_t)(e0 + tid) * 16);
    dst[0] = make_float4(acc[0], acc[1], acc[2], acc[3]);
    dst[1] = make_float4(acc[4], acc[5], acc[6], acc[7]);
    dst[2] = make_float4(acc[8], acc[9], acc[10], acc[11]);
    dst[3] = make_float4(acc[12], acc[13], acc[14], acc[15]);
    return;
  }

  // ===== adj 128x128 tile, BK=32, double-buffered, counted-vmcnt pipeline =====
  int adjid = g * 8 + rem;
  int low3  = adjid & 7, q = adjid >> 3;
  int ti = low3 * 8 + (q & 7);                     // 8 fixed A-panels per XCD
  int tj = ((q >> 6) & 7) * 8 + ((q >> 3) & 7);    // B-panel advances slowly

  int wave = tid >> 6, lane = tid & 63;
  int wr = (wave >> 1) * 64;
  int wc = (wave & 1) * 64;
  int l15 = lane & 15, lg = lane >> 4;

  f32x4 acc[4][4] = {};

  int srow0 = wave * 32 + (lane >> 2);    // staging row (chunk 2w); +16 for chunk 2w+1
  int sp    = lane & 3;                   // physical 16B slot within 64B row

  const size_t rowA = (size_t)(ti * 128) * EMB;
  const size_t rowB = (size_t)(tj * 128) * EMB;

#define STAGE(BUF, KT)                                                          \
  {                                                                             \
    char* base = smem + (BUF) * 16384;                                          \
    int r0 = srow0, r1 = srow0 + 16;                                            \
    int c0 = (KT) * 32 + ((sp ^ ((r0 >> 1) & 3)) << 3);                         \
    int c1 = (KT) * 32 + ((sp ^ ((r1 >> 1) & 3)) << 3);                         \
    gload_lds16(Xb + rowA + (size_t)r0 * EMB + c0, base + wave * 2048);         \
    gload_lds16(Xb + rowA + (size_t)r1 * EMB + c1, base + wave * 2048 + 1024);  \
    gload_lds16(Xb + rowB + (size_t)r0 * EMB + c0, base + 8192 + wave * 2048);  \
    gload_lds16(Xb + rowB + (size_t)r1 * EMB + c1, base + 8192 + wave * 2048 + 1024); \
  }

  STAGE(0, 0)

  #pragma unroll
  for (int kt = 0; kt < 8; ++kt) {
    if (kt < 7) {
      STAGE((kt + 1) & 1, kt + 1)
      asm volatile("s_waitcnt vmcnt(4)" ::: "memory");   // tile kt landed; kt+1 in flight
    } else {
      asm volatile("s_waitcnt vmcnt(0)" ::: "memory");
    }
    __builtin_amdgcn_sched_barrier(0);
    __builtin_amdgcn_s_barrier();          // all waves' tile-kt data visible
    __builtin_amdgcn_sched_barrier(0);

    const char* Ab = smem + (kt & 1) * 16384;
    const char* Bb = Ab + 8192;
    bf16x8 af[4], bfr[4];
    #pragma unroll
    for (int m = 0; m < 4; ++m) {
      int rr = wr + m * 16 + l15;
      af[m] = *(const bf16x8*)(Ab + rr * 64 + ((lg ^ ((rr >> 1) & 3)) << 4));
    }
    #pragma unroll
    for (int n = 0; n < 4; ++n) {
      int rr = wc + n * 16 + l15;
      bfr[n] = *(const bf16x8*)(Bb + rr * 64 + ((lg ^ ((rr >> 1) & 3)) << 4));
    }
    #pragma unroll
    for (int m = 0; m < 4; ++m)
      #pragma unroll
      for (int n = 0; n < 4; ++n)
        acc[m][n] = __builtin_amdgcn_mfma_f32_16x16x32_bf16(af[m], bfr[n], acc[m][n], 0, 0, 0);

    __builtin_amdgcn_sched_barrier(0);
    __builtin_amdgcn_s_barrier();          // reads of buf[kt&1] done -> safe to overwrite
    __builtin_amdgcn_sched_barrier(0);
  }
#undef STAGE

  float W0 = Wp[0], b0 = bp[0];
  float w2 = -2.0f * W0;
  int col0 = tj * 128 + wc + l15;           // j for this lane
  int row0 = ti * 128 + wr + (lg << 2);     // first of 4 consecutive i (per m: +m*16)
  bool diag = (ti == tj);

  float aiW[16];
  #pragma unroll
  for (int m = 0; m < 4; ++m)
    #pragma unroll
    for (int rg = 0; rg < 4; ++rg)
      aiW[m * 4 + rg] = W0 * sq[row0 + m * 16 + rg];

  #pragma unroll
  for (int n = 0; n < 4; ++n) {
    int j = col0 + n * 16;
    float sjW = fmaf(W0, sq[j], b0);
    #pragma unroll
    for (int m = 0; m < 4; ++m) {
      #pragma unroll
      for (int rg = 0; rg < 4; ++rg) {
        float t = fmaf(w2, acc[m][n][rg], aiW[m * 4 + rg] + sjW);
        acc[m][n][rg] = __builtin_amdgcn_rcpf(1.0f + __expf(-t));
      }
      if (diag) {
        #pragma unroll
        for (int rg = 0; rg < 4; ++rg)
          if (row0 + m * 16 + rg == j) acc[m][n][rg] = 0.0f;
      }
      // adj(i,j)=adj(j,i): transposed-square store (NT)
      __builtin_nontemporal_store(acc[m][n],
          (f32x4*)(&adj_out[(size_t)j * NN + row0 + m * 16]));
    }
  }
}

extern "C" void kernel_launch(void* const* d_in, const int* in_sizes, int n_in,
                              void* d_out, int out_size, void* d_ws, size_t ws_size,
                              hipStream_t stream) {
  const float* node_emb = (const float*)d_in[0];
  const float* edge_emb = (const float*)d_in[1];
  const float* node_w   = (const float*)d_in[2];
  const float* node_b   = (const float*)d_in[3];
  const float* edge_w   = (const float*)d_in[4];
  const float* edge_b   = (const float*)d_in[5];
  const float* Wp       = (const float*)d_in[6];
  const float* bp       = (const float*)d_in[7];

  float* out      = (float*)d_out;
  float* node_out = out;                        // [8192 x 64]
  float* edge_out = out + (size_t)NN * 64;      // [131072 x 16]
  float* adj_out  = out + (size_t)NN * 64 + (size_t)NE * 16;  // [8192 x 8192]

  unsigned short* Xb = (unsigned short*)d_ws;                       // 4 MiB
  float* sq = (float*)((char*)d_ws + (size_t)NN * EMB * 2);         // 32 KiB

  node_prep_kernel<<<dim3(512), dim3(256), 0, stream>>>(node_emb, node_w, node_b,
                                                        node_out, Xb, sq);
  mega_kernel<<<dim3(4608), dim3(256), 0, stream>>>(Xb, sq, Wp, bp, adj_out,
                                                    edge_emb, edge_w, edge_b, edge_out);
}